// Round 1
// baseline (3387.486 us; speedup 1.0000x reference)
//
#include <hip/hip_runtime.h>
#include <math.h>

#define N_ATOMS 100000
#define M_NBR 12
#define ORIG_FEA 92
#define NBR_FEA 41
#define AF 64
#define OUT2 128          // 2*AF
#define IN_FULL 169       // 2*AF + NBR_FEA
#define N_CONV 3
#define OUT_DIM 128
#define N_CRYSTALS 2000
#define ATOMS_PER 50
#define EPS 1e-5f

#define ZCH 16            // atoms per block in edge kernels (100000 % 16 == 0)
#define YSN_ATOMS 128     // atoms per block in y kernel
#define YSN_CHUNK 32
#define NF_STRIDE 44      // padded row stride (16B-aligned) for staged nbr_fea

__device__ __forceinline__ float softplus_f(float x) {
    return fmaxf(x, 0.0f) + log1pf(__expf(-fabsf(x)));
}
__device__ __forceinline__ float sigmoid_f(float x) {
    return 1.0f / (1.0f + __expf(-x));
}

// x[n][c] = b[c] + sum_k af[n][k]*W[k][c]   (c<64, k<92)
__global__ __launch_bounds__(256) void k_embed(
    const float* __restrict__ af, const float* __restrict__ W,
    const float* __restrict__ b, float* __restrict__ x) {
  __shared__ float saf[64 * ORIG_FEA];
  int a0 = blockIdx.x * 64;
  int na = min(64, N_ATOMS - a0);
  int tid = threadIdx.x;
  int c = tid & 63, rgrp = tid >> 6;
  float w[ORIG_FEA];
#pragma unroll
  for (int k = 0; k < ORIG_FEA; ++k) w[k] = W[k * AF + c];
  // stage atom_fea chunk (row stride 92 floats = 368B, 16B aligned)
  int n4 = na * (ORIG_FEA / 4);
  const float4* g4 = (const float4*)(af + (size_t)a0 * ORIG_FEA);
  float4* s4 = (float4*)saf;
  for (int e = tid; e < n4; e += 256) s4[e] = g4[e];
  __syncthreads();
  float bc = b[c];
  for (int a = rgrp; a < na; a += 4) {
    float acc = bc;
    const float4* row = (const float4*)(saf + a * ORIG_FEA);
#pragma unroll
    for (int q = 0; q < ORIG_FEA / 4; ++q) {
      float4 v = row[q];
      acc += v.x * w[4 * q] + v.y * w[4 * q + 1] + v.z * w[4 * q + 2] + v.w * w[4 * q + 3];
    }
    x[(size_t)(a0 + a) * AF + c] = acc;
  }
}

// y_self[n][c] = sum_k x[n][k]*Wf[k][c] ; y_nbr[n][c] = sum_k x[n][k]*Wf[64+k][c]
__global__ __launch_bounds__(256) void k_ysn(
    const float* __restrict__ x, const float* __restrict__ Wf,
    float* __restrict__ y_self, float* __restrict__ y_nbr) {
  __shared__ float sx[YSN_CHUNK * AF];
  int tid = threadIdx.x;
  int c = tid & 127, which = tid >> 7;
  float w[AF];
#pragma unroll
  for (int k = 0; k < AF; ++k) w[k] = Wf[(size_t)(which * AF + k) * OUT2 + c];
  float* yout = which ? y_nbr : y_self;
  int abase = blockIdx.x * YSN_ATOMS;
  for (int chk = 0; chk < YSN_ATOMS; chk += YSN_CHUNK) {
    int a0 = abase + chk;
    if (a0 >= N_ATOMS) break;          // uniform per block
    int na = min(YSN_CHUNK, N_ATOMS - a0);
    __syncthreads();
    int n4 = na * (AF / 4);
    const float4* g4 = (const float4*)(x + (size_t)a0 * AF);
    float4* s4 = (float4*)sx;
    for (int e = tid; e < n4; e += 256) s4[e] = g4[e];
    __syncthreads();
    for (int a = 0; a < na; ++a) {
      float acc = 0.f;
      const float4* row = (const float4*)(sx + a * AF);
#pragma unroll
      for (int q = 0; q < AF / 4; ++q) {
        float4 v = row[q];
        acc += v.x * w[4 * q] + v.y * w[4 * q + 1] + v.z * w[4 * q + 2] + v.w * w[4 * q + 3];
      }
      yout[(size_t)(a0 + a) * OUT2 + c] = acc;
    }
  }
}

// Pass 1: compute z rows (recomputed, not stored), accumulate per-channel sum/sumsq.
__global__ __launch_bounds__(256) void k_zstats(
    const float* __restrict__ nbr_fea, const int* __restrict__ nidx,
    const float* __restrict__ y_self, const float* __restrict__ y_nbr,
    const float* __restrict__ Wf, const float* __restrict__ bf,
    float* __restrict__ gsum, float* __restrict__ gsumsq) {
  __shared__ float snf[ZCH * M_NBR * NF_STRIDE];
  __shared__ int sidx[ZCH * M_NBR];
  __shared__ float lsum[OUT2], lsumsq[OUT2];
  int tid = threadIdx.x;
  int ch = tid & 63, rgrp = tid >> 6;
  if (tid < OUT2) { lsum[tid] = 0.f; lsumsq[tid] = 0.f; }
  const float* We = Wf + 2 * AF * OUT2;
  float w0[NBR_FEA], w1[NBR_FEA];
#pragma unroll
  for (int k = 0; k < NBR_FEA; ++k) {
    w0[k] = We[k * OUT2 + ch];
    w1[k] = We[k * OUT2 + AF + ch];
  }
  float b0 = bf[ch], b1 = bf[AF + ch];
  int a0 = blockIdx.x * ZCH;
  int tot = ZCH * M_NBR * NBR_FEA;
  const float* gnf = nbr_fea + (size_t)a0 * M_NBR * NBR_FEA;
  for (int e = tid; e < tot; e += 256) {
    int r = e / NBR_FEA;
    int k = e - r * NBR_FEA;
    snf[r * NF_STRIDE + k] = gnf[e];
  }
  for (int e = tid; e < ZCH * M_NBR; e += 256)
    sidx[e] = nidx[(size_t)a0 * M_NBR + e];
  __syncthreads();
  float s0 = 0.f, q0 = 0.f, s1 = 0.f, q1 = 0.f;
  for (int a = rgrp; a < ZCH; a += 4) {
    int n = a0 + a;
    float ys0 = y_self[(size_t)n * OUT2 + ch];
    float ys1 = y_self[(size_t)n * OUT2 + AF + ch];
    for (int m = 0; m < M_NBR; ++m) {
      int j = sidx[a * M_NBR + m];
      float z0 = ys0 + y_nbr[(size_t)j * OUT2 + ch] + b0;
      float z1 = ys1 + y_nbr[(size_t)j * OUT2 + AF + ch] + b1;
      const float4* row = (const float4*)(snf + (a * M_NBR + m) * NF_STRIDE);
#pragma unroll
      for (int q = 0; q < 10; ++q) {
        float4 v = row[q];
        z0 += v.x * w0[4 * q] + v.y * w0[4 * q + 1] + v.z * w0[4 * q + 2] + v.w * w0[4 * q + 3];
        z1 += v.x * w1[4 * q] + v.y * w1[4 * q + 1] + v.z * w1[4 * q + 2] + v.w * w1[4 * q + 3];
      }
      float vl = snf[(a * M_NBR + m) * NF_STRIDE + 40];
      z0 += vl * w0[40];
      z1 += vl * w1[40];
      s0 += z0; q0 = fmaf(z0, z0, q0);
      s1 += z1; q1 = fmaf(z1, z1, q1);
    }
  }
  atomicAdd(&lsum[ch], s0);      atomicAdd(&lsumsq[ch], q0);
  atomicAdd(&lsum[AF + ch], s1); atomicAdd(&lsumsq[AF + ch], q1);
  __syncthreads();
  if (tid < OUT2) {
    atomicAdd(&gsum[tid], lsum[tid]);
    atomicAdd(&gsumsq[tid], lsumsq[tid]);
  }
}

// Pass 2: recompute z, apply BN1 affine, sigmoid*softplus, sum over m -> s[n][c]; BN2 stats.
__global__ __launch_bounds__(256) void k_apply(
    const float* __restrict__ nbr_fea, const int* __restrict__ nidx,
    const float* __restrict__ y_self, const float* __restrict__ y_nbr,
    const float* __restrict__ Wf, const float* __restrict__ bf,
    const float* __restrict__ sc1, const float* __restrict__ sh1,
    float* __restrict__ s_out, float* __restrict__ gsum, float* __restrict__ gsumsq) {
  __shared__ float snf[ZCH * M_NBR * NF_STRIDE];
  __shared__ int sidx[ZCH * M_NBR];
  __shared__ float lsum[AF], lsumsq[AF];
  int tid = threadIdx.x;
  int ch = tid & 63, rgrp = tid >> 6;
  if (tid < AF) { lsum[tid] = 0.f; lsumsq[tid] = 0.f; }
  const float* We = Wf + 2 * AF * OUT2;
  float w0[NBR_FEA], w1[NBR_FEA];
#pragma unroll
  for (int k = 0; k < NBR_FEA; ++k) {
    w0[k] = We[k * OUT2 + ch];
    w1[k] = We[k * OUT2 + AF + ch];
  }
  float b0 = bf[ch], b1 = bf[AF + ch];
  float f0 = sc1[ch], g0 = sh1[ch];
  float f1 = sc1[AF + ch], g1 = sh1[AF + ch];
  int a0 = blockIdx.x * ZCH;
  int tot = ZCH * M_NBR * NBR_FEA;
  const float* gnf = nbr_fea + (size_t)a0 * M_NBR * NBR_FEA;
  for (int e = tid; e < tot; e += 256) {
    int r = e / NBR_FEA;
    int k = e - r * NBR_FEA;
    snf[r * NF_STRIDE + k] = gnf[e];
  }
  for (int e = tid; e < ZCH * M_NBR; e += 256)
    sidx[e] = nidx[(size_t)a0 * M_NBR + e];
  __syncthreads();
  float ssum = 0.f, ssq = 0.f;
  for (int a = rgrp; a < ZCH; a += 4) {
    int n = a0 + a;
    float ys0 = y_self[(size_t)n * OUT2 + ch];
    float ys1 = y_self[(size_t)n * OUT2 + AF + ch];
    float sacc = 0.f;
    for (int m = 0; m < M_NBR; ++m) {
      int j = sidx[a * M_NBR + m];
      float z0 = ys0 + y_nbr[(size_t)j * OUT2 + ch] + b0;
      float z1 = ys1 + y_nbr[(size_t)j * OUT2 + AF + ch] + b1;
      const float4* row = (const float4*)(snf + (a * M_NBR + m) * NF_STRIDE);
#pragma unroll
      for (int q = 0; q < 10; ++q) {
        float4 v = row[q];
        z0 += v.x * w0[4 * q] + v.y * w0[4 * q + 1] + v.z * w0[4 * q + 2] + v.w * w0[4 * q + 3];
        z1 += v.x * w1[4 * q] + v.y * w1[4 * q + 1] + v.z * w1[4 * q + 2] + v.w * w1[4 * q + 3];
      }
      float vl = snf[(a * M_NBR + m) * NF_STRIDE + 40];
      z0 += vl * w0[40];
      z1 += vl * w1[40];
      z0 = z0 * f0 + g0;                 // BN1 affine (filter half)
      z1 = z1 * f1 + g1;                 // BN1 affine (core half)
      sacc += sigmoid_f(z0) * softplus_f(z1);
    }
    s_out[(size_t)n * AF + ch] = sacc;
    ssum += sacc; ssq = fmaf(sacc, sacc, ssq);
  }
  atomicAdd(&lsum[ch], ssum);
  atomicAdd(&lsumsq[ch], ssq);
  __syncthreads();
  if (tid < AF) {
    atomicAdd(&gsum[tid], lsum[tid]);
    atomicAdd(&gsumsq[tid], lsumsq[tid]);
  }
}

__global__ void k_finalize(const float* __restrict__ gsum, const float* __restrict__ gsumsq,
                           const float* __restrict__ gamma, const float* __restrict__ beta,
                           float* __restrict__ scale, float* __restrict__ shift,
                           int chn, float invcount) {
  int c = threadIdx.x;
  if (c < chn) {
    float m = gsum[c] * invcount;
    float v = gsumsq[c] * invcount - m * m;
    float sc = gamma[c] * rsqrtf(v + EPS);
    scale[c] = sc;
    shift[c] = beta[c] - m * sc;
  }
}

__global__ __launch_bounds__(256) void k_update(
    float* __restrict__ x, const float* __restrict__ s,
    const float* __restrict__ sc2, const float* __restrict__ sh2) {
  int e = blockIdx.x * 256 + threadIdx.x;
  if (e < N_ATOMS * AF) {
    int c = e & (AF - 1);
    float v = x[e] + s[e] * sc2[c] + sh2[c];
    x[e] = softplus_f(v);
  }
}

__global__ __launch_bounds__(128) void k_pool(
    const float* __restrict__ x, const int* __restrict__ cidx,
    const float* __restrict__ Wp, const float* __restrict__ bp,
    float* __restrict__ out) {
  __shared__ float part[2][AF];
  __shared__ float mean[AF];
  int g = blockIdx.x, tid = threadIdx.x;
  int c = tid & 63, h = tid >> 6;
  float acc = 0.f;
  for (int a = h; a < ATOMS_PER; a += 2) {
    int idx = cidx[g * ATOMS_PER + a];
    acc += x[(size_t)idx * AF + c];
  }
  part[h][c] = acc;
  __syncthreads();
  if (tid < AF) mean[tid] = (part[0][tid] + part[1][tid]) * (1.0f / ATOMS_PER);
  __syncthreads();
  float o = bp[tid];
#pragma unroll
  for (int k = 0; k < AF; ++k) o += mean[k] * Wp[k * OUT_DIM + tid];
  out[(size_t)g * OUT_DIM + tid] = fmaxf(o, 0.f);
}

extern "C" void kernel_launch(void* const* d_in, const int* in_sizes, int n_in,
                              void* d_out, int out_size, void* d_ws, size_t ws_size,
                              hipStream_t stream) {
  const float* atom_fea = (const float*)d_in[0];
  const float* nbr_fea  = (const float*)d_in[1];
  const int*   nbr_idx  = (const int*)d_in[2];
  const int*   cidx     = (const int*)d_in[3];
  const float* W_embed  = (const float*)d_in[4];
  const float* b_embed  = (const float*)d_in[5];
  const float* W_full   = (const float*)d_in[6];
  const float* b_full   = (const float*)d_in[7];
  const float* bn1_g    = (const float*)d_in[8];
  const float* bn1_b    = (const float*)d_in[9];
  const float* bn2_g    = (const float*)d_in[10];
  const float* bn2_b    = (const float*)d_in[11];
  const float* W_pool   = (const float*)d_in[12];
  const float* b_pool   = (const float*)d_in[13];
  float* out = (float*)d_out;

  float* ws = (float*)d_ws;
  size_t off = 0;
  float* x      = ws + off; off += (size_t)N_ATOMS * AF;
  float* y_self = ws + off; off += (size_t)N_ATOMS * OUT2;
  float* y_nbr  = ws + off; off += (size_t)N_ATOMS * OUT2;
  float* s_buf  = ws + off; off += (size_t)N_ATOMS * AF;
  float* sums   = ws + off; off += (size_t)N_CONV * 384;   // sum1/sumsq1/sum2/sumsq2
  float* affine = ws + off; off += (size_t)N_CONV * 384;   // sc1/sh1/sc2/sh2

  hipMemsetAsync(sums, 0, (size_t)N_CONV * 384 * sizeof(float), stream);

  k_embed<<<(N_ATOMS + 63) / 64, 256, 0, stream>>>(atom_fea, W_embed, b_embed, x);

  for (int i = 0; i < N_CONV; ++i) {
    const float* Wf = W_full + (size_t)i * IN_FULL * OUT2;
    const float* bf = b_full + (size_t)i * OUT2;
    float* sum1   = sums + (size_t)i * 384;
    float* sumsq1 = sum1 + OUT2;
    float* sum2   = sumsq1 + OUT2;
    float* sumsq2 = sum2 + AF;
    float* sc1 = affine + (size_t)i * 384;
    float* sh1 = sc1 + OUT2;
    float* sc2 = sh1 + OUT2;
    float* sh2 = sc2 + AF;

    k_ysn<<<(N_ATOMS + YSN_ATOMS - 1) / YSN_ATOMS, 256, 0, stream>>>(x, Wf, y_self, y_nbr);
    k_zstats<<<N_ATOMS / ZCH, 256, 0, stream>>>(nbr_fea, nbr_idx, y_self, y_nbr, Wf, bf,
                                                sum1, sumsq1);
    k_finalize<<<1, 128, 0, stream>>>(sum1, sumsq1, bn1_g + i * OUT2, bn1_b + i * OUT2,
                                      sc1, sh1, OUT2, 1.0f / ((float)N_ATOMS * M_NBR));
    k_apply<<<N_ATOMS / ZCH, 256, 0, stream>>>(nbr_fea, nbr_idx, y_self, y_nbr, Wf, bf,
                                               sc1, sh1, s_buf, sum2, sumsq2);
    k_finalize<<<1, 128, 0, stream>>>(sum2, sumsq2, bn2_g + i * AF, bn2_b + i * AF,
                                      sc2, sh2, AF, 1.0f / (float)N_ATOMS);
    k_update<<<(N_ATOMS * AF + 255) / 256, 256, 0, stream>>>(x, s_buf, sc2, sh2);
  }

  k_pool<<<N_CRYSTALS, 128, 0, stream>>>(x, cidx, W_pool, b_pool, out);
}